// Round 7
// baseline (260.448 us; speedup 1.0000x reference)
//
#include <hip/hip_runtime.h>

// B=16, Q=2048, K=2048, D=128, DV=128
// out[b,q,:] = softmax_k((q.k - 0.5||k||^2)/sqrt(192), mask k>=valid_len) @ V
// R7 = R6 (P never touches LDS: C->A layout via one __shfl_xor(32) exchange;
// per-wave key-half PV; epilogue half-merge via LDS) with the scratch bug
// fixed: union replaced by __builtin_bit_cast, pv[] folded into Sv.
// R6 evidence: correctness PASSED, LDS conflicts = 0; only failure was
// scratch traffic (WRITE_SIZE 888MB) from the address-taken union.

#define Bn   16
#define Qn   2048
#define Kn   2048
#define Dn   128
#define DVn  128
#define BQ   64
#define BK   64

// (1/sqrt(192)) * log2(e) : softmax computed as 2^(qk*SC2 + bias2)
#define SC2 0.10411754f

typedef short bf16x4 __attribute__((ext_vector_type(4)));
typedef short bf16x8 __attribute__((ext_vector_type(8)));
typedef float f32x16 __attribute__((ext_vector_type(16)));

__device__ __forceinline__ short f2bf(float x) {   // RNE
    union { float f; unsigned u; } v; v.f = x;
    unsigned r = (v.u + 0x7fffu + ((v.u >> 16) & 1u)) >> 16;
    return (short)r;
}

typedef const __attribute__((address_space(1))) void* gas_t;
typedef __attribute__((address_space(3))) void* las_t;
__device__ __forceinline__ void gld16(const void* g, void* l) {
    __builtin_amdgcn_global_load_lds((gas_t)g, (las_t)l, 16, 0, 0);
}
__device__ __forceinline__ void gld4(const void* g, void* l) {
    __builtin_amdgcn_global_load_lds((gas_t)g, (las_t)l, 4, 0, 0);
}
__device__ __forceinline__ float exp2_raw(float a) {  // D = 2^S0
    float p;
    asm("v_exp_f32 %0, %1" : "=v"(p) : "v"(a));
    return p;
}

// ---------- preprocess (identical to R4/R6) ----------
__global__ __launch_bounds__(256) void prep_kv(const float* __restrict__ Kg,
                                               const float* __restrict__ Vg,
                                               short* __restrict__ Kb,
                                               short* __restrict__ Vtb,
                                               float* __restrict__ biasg) {
    __shared__ short Ls[64 * 128];
    const int tid = threadIdx.x;
    if (blockIdx.x < 512) {
        const int b  = blockIdx.x >> 5;
        const int k0 = (blockIdx.x & 31) * 64;
        const int row = k0 + (tid >> 2);
        const int c   = (tid & 3) * 32;
        const float* src = Kg + ((size_t)b * Kn + row) * Dn + c;
        short*       dst = Kb + ((size_t)b * Kn + row) * Dn + c;
        float ssq = 0.f;
#pragma unroll
        for (int j = 0; j < 4; ++j) {
            float4 x0 = *(const float4*)(src + j * 8);
            float4 x1 = *(const float4*)(src + j * 8 + 4);
            ssq += x0.x*x0.x + x0.y*x0.y + x0.z*x0.z + x0.w*x0.w
                 + x1.x*x1.x + x1.y*x1.y + x1.z*x1.z + x1.w*x1.w;
            bf16x8 h;
            h[0]=f2bf(x0.x); h[1]=f2bf(x0.y); h[2]=f2bf(x0.z); h[3]=f2bf(x0.w);
            h[4]=f2bf(x1.x); h[5]=f2bf(x1.y); h[6]=f2bf(x1.z); h[7]=f2bf(x1.w);
            *(bf16x8*)(dst + j * 8) = h;
        }
        ssq += __shfl_xor(ssq, 1);
        ssq += __shfl_xor(ssq, 2);
        if ((tid & 3) == 0) biasg[b * Kn + row] = -0.5f * ssq * SC2;
    } else {
        const int blk = blockIdx.x - 512;
        const int b  = blk >> 5;
        const int k0 = (blk & 31) * 64;
        {
            const int key = tid >> 2;
            const float* src = Vg + ((size_t)b * Kn + k0 + key) * DVn + (tid & 3) * 32;
#pragma unroll
            for (int cj = 0; cj < 4; ++cj) {
                float4 x0 = *(const float4*)(src + cj * 8);
                float4 x1 = *(const float4*)(src + cj * 8 + 4);
                bf16x8 h;
                h[0]=f2bf(x0.x); h[1]=f2bf(x0.y); h[2]=f2bf(x0.z); h[3]=f2bf(x0.w);
                h[4]=f2bf(x1.x); h[5]=f2bf(x1.y); h[6]=f2bf(x1.z); h[7]=f2bf(x1.w);
                const int ch = (tid & 3) * 4 + cj;
                const int sw = (ch + key) & 15;
                *(bf16x8*)&Ls[key * 128 + sw * 8] = h;
            }
        }
        __syncthreads();
        {
            const int v = tid >> 1;
            const int h = (tid & 1) * 32;
            short tmp[32];
#pragma unroll
            for (int j = 0; j < 32; ++j) {
                const int kk = h + j;
                const int sw = ((v >> 3) + kk) & 15;
                tmp[j] = Ls[kk * 128 + sw * 8 + (v & 7)];
            }
            short* dst = Vtb + ((size_t)b * DVn + v) * Kn + k0 + h;
#pragma unroll
            for (int j = 0; j < 4; ++j)
                *(bf16x8*)(dst + j * 8) = *(bf16x8*)(tmp + j * 8);
        }
    }
}

// ---------- main attention kernel ----------
__global__ __launch_bounds__(256, 2) void attn_kernel(
    const float* __restrict__ Qg, const short* __restrict__ Kb,
    const short* __restrict__ Vtb, const float* __restrict__ biasg,
    const int* __restrict__ VL, float* __restrict__ Og)
{
    // K tile: 64 rows x 256B, chunk XOR by (row&15)
    // V tile: 64 rows x 256B; row r holds v=2r (slots c<8) and v=2r+1 (c>=8),
    //         slot position p = c ^ (r&15)
    __shared__ __align__(16) short Ksh[2][64 * 128];   // 32768 B (epilogue: float slab)
    __shared__ __align__(16) short Vsh[2][64 * 128];   // 32768 B
    __shared__ __align__(16) float biasSh[2][64];      //   512 B
    __shared__ float Lsum[4][32];                      //   512 B -> 66560 B total

    const int tid  = threadIdx.x;
    const int lane = tid & 63;
    const int w    = tid >> 6;    // wave 0..3
    const int pair = w >> 1;      // q-strip: rows [pair*32, pair*32+32)
    const int half = w & 1;       // key-half (S and PV k-range)
    const int l31  = lane & 31;
    const int hi   = lane >> 5;

    const int lin  = blockIdx.x;          // 0..511 ; XCD swizzle
    const int slot = lin >> 3;
    const int b    = (lin & 7) * 2 + (slot >> 5);
    const int q0   = (slot & 31) * BQ;

    const short* Kb_b = Kb  + (size_t)b * Kn * Dn;
    const short* Vt_b = Vtb + (size_t)b * DVn * Kn;
    const float* bias_b = biasg + b * Kn;

    // ---- DMA source pointers ----
    const short* ksp[4]; int kdo[4];
    const short* vsp[4]; int vdo[4];
#pragma unroll
    for (int i = 0; i < 4; ++i) {
        const int rl = w * 16 + i * 4 + (lane >> 4);       // K tile row 0..63
        const int ch = (lane & 15) ^ (rl & 15);
        ksp[i] = Kb_b + (size_t)rl * Dn + ch * 8;
        kdo[i] = (w * 16 + i * 4) * 128;
        const int rv = w * 16 + i * 4 + (lane >> 4);       // V tile row 0..63
        const int cc = (lane & 15) ^ (rv & 15);            // source chunk
        const int vv = 2 * rv + (cc >> 3);
        vsp[i] = Vt_b + (size_t)vv * Kn + (cc & 7) * 8;
        vdo[i] = (w * 16 + i * 4) * 128;
    }

    // ---- Q fragments: frag layout [n=l31][k=kt*16+hi*8+j] ----
    bf16x8 qf[8];
    {
        const float* qrow = Qg + ((size_t)b * Qn + q0 + pair * 32 + l31) * Dn;
#pragma unroll
        for (int kt = 0; kt < 8; ++kt) {
            const float* p = qrow + kt * 16 + hi * 8;
            float4 x0 = *(const float4*)(p);
            float4 x1 = *(const float4*)(p + 4);
            bf16x8 f;
            f[0]=f2bf(x0.x); f[1]=f2bf(x0.y); f[2]=f2bf(x0.z); f[3]=f2bf(x0.w);
            f[4]=f2bf(x1.x); f[5]=f2bf(x1.y); f[6]=f2bf(x1.z); f[7]=f2bf(x1.w);
            qf[kt] = f;
        }
    }
    const int vlq = VL[b * Qn + q0 + pair * 32 + l31];

    f32x16 Oacc[4];   // v = nt*32 + l31, all 128 v; keys restricted to own half
#pragma unroll
    for (int nt = 0; nt < 4; ++nt)
#pragma unroll
        for (int j = 0; j < 16; ++j) Oacc[nt][j] = 0.f;
    float psum = 0.f;

    // prologue: DMA tile 0 into buffer 0
#pragma unroll
    for (int i = 0; i < 4; ++i) {
        gld16(ksp[i], &Ksh[0][kdo[i]]);
        gld16(vsp[i], &Vsh[0][vdo[i]]);
    }
    if (w == 0) gld4(bias_b + lane, &biasSh[0][0]);

    for (int k0k = 0; k0k < Kn; k0k += BK) {
        const int buf = (k0k >> 6) & 1;
        __syncthreads();   // drains vmcnt(0): tile ready; prev readers done

        if (k0k + BK < Kn) {
            const int nk = k0k + BK;
#pragma unroll
            for (int i = 0; i < 4; ++i) {
                gld16(ksp[i] + (size_t)nk * Dn, &Ksh[buf ^ 1][kdo[i]]);
                gld16(vsp[i] + nk,              &Vsh[buf ^ 1][vdo[i]]);
            }
            if (w == 0) gld4(bias_b + nk + lane, &biasSh[buf ^ 1][0]);
        }

        float4 bv[4];
#pragma unroll
        for (int rq = 0; rq < 4; ++rq)
            bv[rq] = *(const float4*)&biasSh[buf][half * 32 + rq * 8 + hi * 4];

        // ---- S^T = K_half . Q^T : one 32x32 tile per wave (8 MFMA) ----
        const short* kbuf = Ksh[buf];
        const int kr = half * 32 + l31;
        f32x16 Sv;
#pragma unroll
        for (int j = 0; j < 16; ++j) Sv[j] = 0.f;
#pragma unroll
        for (int kt = 0; kt < 8; ++kt) {
            bf16x8 kf = *(const bf16x8*)&kbuf[kr * 128 + (((kt*2 + hi) ^ (kr & 15)) * 8)];
            Sv = __builtin_amdgcn_mfma_f32_32x32x16_bf16(kf, qf[kt], Sv, 0, 0, 0);
        }

        // ---- softmax in exp2 domain (results back into Sv) ----
#pragma unroll
        for (int rq = 0; rq < 4; ++rq) {
#pragma unroll
            for (int r = 0; r < 4; ++r) {
                const int reg = rq * 4 + r;
                const int keyg = k0k + half * 32 + rq * 8 + hi * 4 + r;
                float a = fmaf(Sv[reg], SC2, bv[rq][r]);
                a = (keyg < vlq) ? a : -200.0f;
                const float p = exp2_raw(a);
                psum += p;
                Sv[reg] = p;
            }
        }

        // ---- PV: C-layout -> A-layout via lane^32 exchange; 8 MFMA ----
        const short* vbuf = Vsh[buf];
#pragma unroll
        for (int kt = 0; kt < 2; ++kt) {
            // kA = pack(C[rq=2kt][0..3]), kB = pack(C[rq=2kt+1][0..3])
            unsigned kAx = __builtin_amdgcn_perm(__float_as_uint(Sv[(2*kt)*4+1]),
                                                 __float_as_uint(Sv[(2*kt)*4+0]), 0x07060302u);
            unsigned kAy = __builtin_amdgcn_perm(__float_as_uint(Sv[(2*kt)*4+3]),
                                                 __float_as_uint(Sv[(2*kt)*4+2]), 0x07060302u);
            unsigned kBx = __builtin_amdgcn_perm(__float_as_uint(Sv[(2*kt+1)*4+1]),
                                                 __float_as_uint(Sv[(2*kt+1)*4+0]), 0x07060302u);
            unsigned kBy = __builtin_amdgcn_perm(__float_as_uint(Sv[(2*kt+1)*4+3]),
                                                 __float_as_uint(Sv[(2*kt+1)*4+2]), 0x07060302u);
            // partner (lane^32) needs the rq-block matching its own hi
            const unsigned sx = hi ? kAx : kBx;
            const unsigned sy = hi ? kAy : kBy;
            const unsigned rx = __shfl_xor(sx, 32);
            const unsigned ry = __shfl_xor(sy, 32);
            uint4 au;
            au.x = hi ? rx : kAx;
            au.y = hi ? ry : kAy;
            au.z = hi ? kBx : rx;
            au.w = hi ? kBy : ry;
            const bf16x8 af = __builtin_bit_cast(bf16x8, au);
            const int kc = half * 4 + kt * 2 + hi;   // key-chunk within 64-key tile
#pragma unroll
            for (int nt = 0; nt < 4; ++nt) {
                const int v  = nt * 32 + l31;
                const int r  = v >> 1;
                const int p  = ((v & 1) * 8 + kc) ^ (r & 15);
                bf16x8 vf = *(const bf16x8*)&vbuf[r * 128 + p * 8];
                Oacc[nt] = __builtin_amdgcn_mfma_f32_32x32x16_bf16(af, vf, Oacc[nt], 0, 0, 0);
            }
        }
    }

    // ---- epilogue: combine key-halves across wave pairs via LDS ----
    psum += __shfl_xor(psum, 32);
    if (lane < 32) Lsum[w][l31] = psum;
    __syncthreads();   // all waves done reading Ksh/Vsh -> safe to reuse Ksh

    float* slab = (float*)&Ksh[0][0];
    // write the half the PARTNER will store: nt in {2*(1-half), 2*(1-half)+1}
#pragma unroll
    for (int i = 0; i < 2; ++i) {
        const int nt = 2 * (1 - half) + i;
        float* dst = slab + ((pair * 2 + (1 - half)) * 2 + i) * 1024;
#pragma unroll
        for (int reg = 0; reg < 16; ++reg) {
            const int row = (reg & 3) + 8 * (reg >> 2) + 4 * hi;
            dst[row * 32 + l31] = Oacc[nt][reg];
        }
    }
    __syncthreads();

    float invl[16];
#pragma unroll
    for (int rq = 0; rq < 4; ++rq)
#pragma unroll
        for (int r = 0; r < 4; ++r) {
            const int ql = r + 8 * rq + 4 * hi;
            invl[rq*4+r] = 1.f / (Lsum[pair*2][ql] + Lsum[pair*2+1][ql]);
        }
    float* obase = Og + ((size_t)b * Qn + q0 + pair * 32) * DVn;
#pragma unroll
    for (int i = 0; i < 2; ++i) {
        const int nt = 2 * half + i;
        const float* src = slab + ((pair * 2 + half) * 2 + i) * 1024;
#pragma unroll
        for (int reg = 0; reg < 16; ++reg) {
            const int row = (reg & 3) + 8 * (reg >> 2) + 4 * hi;
            const int col = half * 64 + i * 32 + l31;
            const float o = Oacc[nt][reg] + src[row * 32 + l31];
            obase[(size_t)row * DVn + col] = o * invl[reg];
        }
    }
}

extern "C" void kernel_launch(void* const* d_in, const int* in_sizes, int n_in,
                              void* d_out, int out_size, void* d_ws, size_t ws_size,
                              hipStream_t stream) {
    const float* Qg = (const float*)d_in[0];
    const float* Kg = (const float*)d_in[1];
    const float* Vg = (const float*)d_in[2];
    const int*   VL = (const int*)d_in[3];
    float* Og = (float*)d_out;

    // ws: Kb bf16 (8MB) | Vtb bf16 (8MB) | bias2 f32 (128KB)
    char* ws = (char*)d_ws;
    short* Kb   = (short*)(ws);
    short* Vtb  = (short*)(ws + (size_t)Bn * Kn * Dn * 2);
    float* bias = (float*)(ws + (size_t)Bn * Kn * Dn * 4);

    prep_kv<<<dim3(1024), dim3(256), 0, stream>>>(Kg, Vg, Kb, Vtb, bias);
    attn_kernel<<<dim3(512), dim3(256), 0, stream>>>(Qg, Kb, Vtb, bias, VL, Og);
}

// Round 8
// 148.499 us; speedup vs baseline: 1.7539x; 1.7539x over previous
//
#include <hip/hip_runtime.h>

// B=16, Q=2048, K=2048, D=128, DV=128
// out[b,q,:] = softmax_k((q.k - 0.5||k||^2)/sqrt(192), mask k>=valid_len) @ V
// R8 = R7 with the REAL scratch bug fixed: the epilogue indexed Oacc[] with a
// runtime index (2*half+i), which demoted the accumulator array to scratch for
// the whole kernel (R6/R7's 880MB WRITE_SIZE). half is wave-uniform, so the
// epilogue is now a uniform branch with literal Oacc indices only.

#define Bn   16
#define Qn   2048
#define Kn   2048
#define Dn   128
#define DVn  128
#define BQ   64
#define BK   64

// (1/sqrt(192)) * log2(e) : softmax computed as 2^(qk*SC2 + bias2)
#define SC2 0.10411754f

typedef short bf16x4 __attribute__((ext_vector_type(4)));
typedef short bf16x8 __attribute__((ext_vector_type(8)));
typedef float f32x16 __attribute__((ext_vector_type(16)));

__device__ __forceinline__ short f2bf(float x) {   // RNE
    union { float f; unsigned u; } v; v.f = x;
    unsigned r = (v.u + 0x7fffu + ((v.u >> 16) & 1u)) >> 16;
    return (short)r;
}

typedef const __attribute__((address_space(1))) void* gas_t;
typedef __attribute__((address_space(3))) void* las_t;
__device__ __forceinline__ void gld16(const void* g, void* l) {
    __builtin_amdgcn_global_load_lds((gas_t)g, (las_t)l, 16, 0, 0);
}
__device__ __forceinline__ void gld4(const void* g, void* l) {
    __builtin_amdgcn_global_load_lds((gas_t)g, (las_t)l, 4, 0, 0);
}
__device__ __forceinline__ float exp2_raw(float a) {  // D = 2^S0
    float p;
    asm("v_exp_f32 %0, %1" : "=v"(p) : "v"(a));
    return p;
}

// ---------- preprocess (identical to R4/R6/R7) ----------
__global__ __launch_bounds__(256) void prep_kv(const float* __restrict__ Kg,
                                               const float* __restrict__ Vg,
                                               short* __restrict__ Kb,
                                               short* __restrict__ Vtb,
                                               float* __restrict__ biasg) {
    __shared__ short Ls[64 * 128];
    const int tid = threadIdx.x;
    if (blockIdx.x < 512) {
        const int b  = blockIdx.x >> 5;
        const int k0 = (blockIdx.x & 31) * 64;
        const int row = k0 + (tid >> 2);
        const int c   = (tid & 3) * 32;
        const float* src = Kg + ((size_t)b * Kn + row) * Dn + c;
        short*       dst = Kb + ((size_t)b * Kn + row) * Dn + c;
        float ssq = 0.f;
#pragma unroll
        for (int j = 0; j < 4; ++j) {
            float4 x0 = *(const float4*)(src + j * 8);
            float4 x1 = *(const float4*)(src + j * 8 + 4);
            ssq += x0.x*x0.x + x0.y*x0.y + x0.z*x0.z + x0.w*x0.w
                 + x1.x*x1.x + x1.y*x1.y + x1.z*x1.z + x1.w*x1.w;
            bf16x8 h;
            h[0]=f2bf(x0.x); h[1]=f2bf(x0.y); h[2]=f2bf(x0.z); h[3]=f2bf(x0.w);
            h[4]=f2bf(x1.x); h[5]=f2bf(x1.y); h[6]=f2bf(x1.z); h[7]=f2bf(x1.w);
            *(bf16x8*)(dst + j * 8) = h;
        }
        ssq += __shfl_xor(ssq, 1);
        ssq += __shfl_xor(ssq, 2);
        if ((tid & 3) == 0) biasg[b * Kn + row] = -0.5f * ssq * SC2;
    } else {
        const int blk = blockIdx.x - 512;
        const int b  = blk >> 5;
        const int k0 = (blk & 31) * 64;
        {
            const int key = tid >> 2;
            const float* src = Vg + ((size_t)b * Kn + k0 + key) * DVn + (tid & 3) * 32;
#pragma unroll
            for (int cj = 0; cj < 4; ++cj) {
                float4 x0 = *(const float4*)(src + cj * 8);
                float4 x1 = *(const float4*)(src + cj * 8 + 4);
                bf16x8 h;
                h[0]=f2bf(x0.x); h[1]=f2bf(x0.y); h[2]=f2bf(x0.z); h[3]=f2bf(x0.w);
                h[4]=f2bf(x1.x); h[5]=f2bf(x1.y); h[6]=f2bf(x1.z); h[7]=f2bf(x1.w);
                const int ch = (tid & 3) * 4 + cj;
                const int sw = (ch + key) & 15;
                *(bf16x8*)&Ls[key * 128 + sw * 8] = h;
            }
        }
        __syncthreads();
        {
            const int v = tid >> 1;
            const int h = (tid & 1) * 32;
            short tmp[32];
#pragma unroll
            for (int j = 0; j < 32; ++j) {
                const int kk = h + j;
                const int sw = ((v >> 3) + kk) & 15;
                tmp[j] = Ls[kk * 128 + sw * 8 + (v & 7)];
            }
            short* dst = Vtb + ((size_t)b * DVn + v) * Kn + k0 + h;
#pragma unroll
            for (int j = 0; j < 4; ++j)
                *(bf16x8*)(dst + j * 8) = *(bf16x8*)(tmp + j * 8);
        }
    }
}

// epilogue helpers with LITERAL accumulator indices (no runtime Oacc[] index)
#define DUMP_ACC(ACC, DST)                                            \
    {                                                                 \
        _Pragma("unroll")                                             \
        for (int reg = 0; reg < 16; ++reg) {                          \
            const int row = (reg & 3) + 8 * (reg >> 2) + 4 * hi;      \
            (DST)[row * 32 + l31] = (ACC)[reg];                       \
        }                                                             \
    }
#define STORE_ACC(ACC, SRC, COLBASE)                                  \
    {                                                                 \
        _Pragma("unroll")                                             \
        for (int reg = 0; reg < 16; ++reg) {                          \
            const int row = (reg & 3) + 8 * (reg >> 2) + 4 * hi;      \
            const float o = (ACC)[reg] + (SRC)[row * 32 + l31];       \
            obase[(size_t)row * DVn + (COLBASE) + l31] = o * invl[reg]; \
        }                                                             \
    }

// ---------- main attention kernel ----------
__global__ __launch_bounds__(256, 2) void attn_kernel(
    const float* __restrict__ Qg, const short* __restrict__ Kb,
    const short* __restrict__ Vtb, const float* __restrict__ biasg,
    const int* __restrict__ VL, float* __restrict__ Og)
{
    // K tile: 64 rows x 256B, chunk XOR by (row&15)
    // V tile: 64 rows x 256B; row r holds v=2r (slots c<8) and v=2r+1 (c>=8),
    //         slot position p = c ^ (r&15)
    __shared__ __align__(16) short Ksh[2][64 * 128];   // 32768 B (epilogue: float slab)
    __shared__ __align__(16) short Vsh[2][64 * 128];   // 32768 B
    __shared__ __align__(16) float biasSh[2][64];      //   512 B
    __shared__ float Lsum[4][32];                      //   512 B -> 66560 B total

    const int tid  = threadIdx.x;
    const int lane = tid & 63;
    const int w    = tid >> 6;    // wave 0..3
    const int pair = w >> 1;      // q-strip: rows [pair*32, pair*32+32)
    const int half = w & 1;       // key-half (S and PV k-range), wave-uniform
    const int l31  = lane & 31;
    const int hi   = lane >> 5;

    const int lin  = blockIdx.x;          // 0..511 ; XCD swizzle
    const int slot = lin >> 3;
    const int b    = (lin & 7) * 2 + (slot >> 5);
    const int q0   = (slot & 31) * BQ;

    const short* Kb_b = Kb  + (size_t)b * Kn * Dn;
    const short* Vt_b = Vtb + (size_t)b * DVn * Kn;
    const float* bias_b = biasg + b * Kn;

    // ---- DMA source pointers ----
    const short* ksp[4]; int kdo[4];
    const short* vsp[4]; int vdo[4];
#pragma unroll
    for (int i = 0; i < 4; ++i) {
        const int rl = w * 16 + i * 4 + (lane >> 4);       // K tile row 0..63
        const int ch = (lane & 15) ^ (rl & 15);
        ksp[i] = Kb_b + (size_t)rl * Dn + ch * 8;
        kdo[i] = (w * 16 + i * 4) * 128;
        const int rv = w * 16 + i * 4 + (lane >> 4);       // V tile row 0..63
        const int cc = (lane & 15) ^ (rv & 15);            // source chunk
        const int vv = 2 * rv + (cc >> 3);
        vsp[i] = Vt_b + (size_t)vv * Kn + (cc & 7) * 8;
        vdo[i] = (w * 16 + i * 4) * 128;
    }

    // ---- Q fragments: frag layout [n=l31][k=kt*16+hi*8+j] ----
    bf16x8 qf[8];
    {
        const float* qrow = Qg + ((size_t)b * Qn + q0 + pair * 32 + l31) * Dn;
#pragma unroll
        for (int kt = 0; kt < 8; ++kt) {
            const float* p = qrow + kt * 16 + hi * 8;
            float4 x0 = *(const float4*)(p);
            float4 x1 = *(const float4*)(p + 4);
            bf16x8 f;
            f[0]=f2bf(x0.x); f[1]=f2bf(x0.y); f[2]=f2bf(x0.z); f[3]=f2bf(x0.w);
            f[4]=f2bf(x1.x); f[5]=f2bf(x1.y); f[6]=f2bf(x1.z); f[7]=f2bf(x1.w);
            qf[kt] = f;
        }
    }
    const int vlq = VL[b * Qn + q0 + pair * 32 + l31];

    f32x16 Oacc[4];   // v = nt*32 + l31, all 128 v; keys restricted to own half
#pragma unroll
    for (int nt = 0; nt < 4; ++nt)
#pragma unroll
        for (int j = 0; j < 16; ++j) Oacc[nt][j] = 0.f;
    float psum = 0.f;

    // prologue: DMA tile 0 into buffer 0
#pragma unroll
    for (int i = 0; i < 4; ++i) {
        gld16(ksp[i], &Ksh[0][kdo[i]]);
        gld16(vsp[i], &Vsh[0][vdo[i]]);
    }
    if (w == 0) gld4(bias_b + lane, &biasSh[0][0]);

    for (int k0k = 0; k0k < Kn; k0k += BK) {
        const int buf = (k0k >> 6) & 1;
        __syncthreads();   // drains vmcnt(0): tile ready; prev readers done

        if (k0k + BK < Kn) {
            const int nk = k0k + BK;
#pragma unroll
            for (int i = 0; i < 4; ++i) {
                gld16(ksp[i] + (size_t)nk * Dn, &Ksh[buf ^ 1][kdo[i]]);
                gld16(vsp[i] + nk,              &Vsh[buf ^ 1][vdo[i]]);
            }
            if (w == 0) gld4(bias_b + nk + lane, &biasSh[buf ^ 1][0]);
        }

        float4 bv[4];
#pragma unroll
        for (int rq = 0; rq < 4; ++rq)
            bv[rq] = *(const float4*)&biasSh[buf][half * 32 + rq * 8 + hi * 4];

        // ---- S^T = K_half . Q^T : one 32x32 tile per wave (8 MFMA) ----
        const short* kbuf = Ksh[buf];
        const int kr = half * 32 + l31;
        f32x16 Sv;
#pragma unroll
        for (int j = 0; j < 16; ++j) Sv[j] = 0.f;
#pragma unroll
        for (int kt = 0; kt < 8; ++kt) {
            bf16x8 kf = *(const bf16x8*)&kbuf[kr * 128 + (((kt*2 + hi) ^ (kr & 15)) * 8)];
            Sv = __builtin_amdgcn_mfma_f32_32x32x16_bf16(kf, qf[kt], Sv, 0, 0, 0);
        }

        // ---- softmax in exp2 domain (results back into Sv) ----
#pragma unroll
        for (int rq = 0; rq < 4; ++rq) {
#pragma unroll
            for (int r = 0; r < 4; ++r) {
                const int reg = rq * 4 + r;
                const int keyg = k0k + half * 32 + rq * 8 + hi * 4 + r;
                float a = fmaf(Sv[reg], SC2, bv[rq][r]);
                a = (keyg < vlq) ? a : -200.0f;
                const float p = exp2_raw(a);
                psum += p;
                Sv[reg] = p;
            }
        }

        // ---- PV: C-layout -> A-layout via lane^32 exchange; 8 MFMA ----
        const short* vbuf = Vsh[buf];
#pragma unroll
        for (int kt = 0; kt < 2; ++kt) {
            unsigned kAx = __builtin_amdgcn_perm(__float_as_uint(Sv[(2*kt)*4+1]),
                                                 __float_as_uint(Sv[(2*kt)*4+0]), 0x07060302u);
            unsigned kAy = __builtin_amdgcn_perm(__float_as_uint(Sv[(2*kt)*4+3]),
                                                 __float_as_uint(Sv[(2*kt)*4+2]), 0x07060302u);
            unsigned kBx = __builtin_amdgcn_perm(__float_as_uint(Sv[(2*kt+1)*4+1]),
                                                 __float_as_uint(Sv[(2*kt+1)*4+0]), 0x07060302u);
            unsigned kBy = __builtin_amdgcn_perm(__float_as_uint(Sv[(2*kt+1)*4+3]),
                                                 __float_as_uint(Sv[(2*kt+1)*4+2]), 0x07060302u);
            const unsigned sx = hi ? kAx : kBx;
            const unsigned sy = hi ? kAy : kBy;
            const unsigned rx = __shfl_xor(sx, 32);
            const unsigned ry = __shfl_xor(sy, 32);
            uint4 au;
            au.x = hi ? rx : kAx;
            au.y = hi ? ry : kAy;
            au.z = hi ? kBx : rx;
            au.w = hi ? kBy : ry;
            const bf16x8 af = __builtin_bit_cast(bf16x8, au);
            const int kc = half * 4 + kt * 2 + hi;   // key-chunk within 64-key tile
#pragma unroll
            for (int nt = 0; nt < 4; ++nt) {
                const int v  = nt * 32 + l31;
                const int r  = v >> 1;
                const int p  = ((v & 1) * 8 + kc) ^ (r & 15);
                bf16x8 vf = *(const bf16x8*)&vbuf[r * 128 + p * 8];
                Oacc[nt] = __builtin_amdgcn_mfma_f32_32x32x16_bf16(af, vf, Oacc[nt], 0, 0, 0);
            }
        }
    }

    // ---- epilogue: combine key-halves across wave pairs via LDS ----
    psum += __shfl_xor(psum, 32);
    if (lane < 32) Lsum[w][l31] = psum;
    __syncthreads();   // all waves done reading Ksh/Vsh -> safe to reuse Ksh

    float* slab = (float*)&Ksh[0][0];
    // write the half the PARTNER will store (literal Oacc indices; half is
    // wave-uniform so this is a scalar branch, not divergence)
    {
        float* dst0 = slab + ((pair * 2 + (1 - half)) * 2 + 0) * 1024;
        float* dst1 = slab + ((pair * 2 + (1 - half)) * 2 + 1) * 1024;
        if (half == 0) {
            DUMP_ACC(Oacc[2], dst0);
            DUMP_ACC(Oacc[3], dst1);
        } else {
            DUMP_ACC(Oacc[0], dst0);
            DUMP_ACC(Oacc[1], dst1);
        }
    }
    __syncthreads();

    float invl[16];
#pragma unroll
    for (int rq = 0; rq < 4; ++rq)
#pragma unroll
        for (int r = 0; r < 4; ++r) {
            const int ql = r + 8 * rq + 4 * hi;
            invl[rq*4+r] = 1.f / (Lsum[pair*2][ql] + Lsum[pair*2+1][ql]);
        }
    float* obase = Og + ((size_t)b * Qn + q0 + pair * 32) * DVn;
    {
        const float* src0 = slab + ((pair * 2 + half) * 2 + 0) * 1024;
        const float* src1 = slab + ((pair * 2 + half) * 2 + 1) * 1024;
        if (half == 0) {
            STORE_ACC(Oacc[0], src0, 0);
            STORE_ACC(Oacc[1], src1, 32);
        } else {
            STORE_ACC(Oacc[2], src0, 64);
            STORE_ACC(Oacc[3], src1, 96);
        }
    }
}

extern "C" void kernel_launch(void* const* d_in, const int* in_sizes, int n_in,
                              void* d_out, int out_size, void* d_ws, size_t ws_size,
                              hipStream_t stream) {
    const float* Qg = (const float*)d_in[0];
    const float* Kg = (const float*)d_in[1];
    const float* Vg = (const float*)d_in[2];
    const int*   VL = (const int*)d_in[3];
    float* Og = (float*)d_out;

    // ws: Kb bf16 (8MB) | Vtb bf16 (8MB) | bias2 f32 (128KB)
    char* ws = (char*)d_ws;
    short* Kb   = (short*)(ws);
    short* Vtb  = (short*)(ws + (size_t)Bn * Kn * Dn * 2);
    float* bias = (float*)(ws + (size_t)Bn * Kn * Dn * 4);

    prep_kv<<<dim3(1024), dim3(256), 0, stream>>>(Kg, Vg, Kb, Vtb, bias);
    attn_kernel<<<dim3(512), dim3(256), 0, stream>>>(Qg, Kb, Vtb, bias, VL, Og);
}